// Round 11
// baseline (483.139 us; speedup 1.0000x reference)
//
#include <hip/hip_runtime.h>
#include <math.h>

// ---- problem constants ----
#define TB        256           // threads per block = 4 waves
#define POSB      256           // positions per block (4 waves x 4 pos-tiles x 16)
#define NPOS      131072        // B*H*W positions
#define KCODES    512
#define DIM       64
#define HW        4096          // H*W
#define LOSS_OFF  8388608ull
#define ENC_OFF   8388609ull
#define PERP_OFF  75497473ull
#define TILE_DW   (POSB * KCODES)       // 131072 dwords: block's encodings tile
#define NF4       ((TILE_DW - 4) / 4)   // 32767 float4 after the +3 align shift
#define TAU       2.0e-4f               // rigorous screen slack (R12 notes)
#define NBLK      (NPOS / POSB)         // 512 main blocks

typedef __attribute__((ext_vector_type(8))) short bf16x8;   // 8 bf16 = 4 VGPR
typedef __attribute__((ext_vector_type(4))) float f32x4;

__device__ __forceinline__ float tree8(float r0, float r1, float r2, float r3,
                                       float r4, float r5, float r6, float r7) {
    // numpy pairwise combine: ((r0+r1)+(r2+r3)) + ((r4+r5)+(r6+r7))
    return __fadd_rn(__fadd_rn(__fadd_rn(r0, r1), __fadd_rn(r2, r3)),
                     __fadd_rn(__fadd_rn(r4, r5), __fadd_rn(r6, r7)));
}

// Prep (R15-parallel): blocks 0..31 pack code-tile ct's B-fragments with
// coalesced 16B stores; block 32 does exact pairwise ww + zero-init (now
// including the last-block-done counter for the fused finalize).
// Fragment convention identical to R12-R15: lane lf holds col n=lf&15,
// kslot=(lf>>4)*8+j8, channel d=q*32+kslot; hi=top-16-bits, lo=trunc(v-hi).
extern "C" __global__ __launch_bounds__(512)
void vq_prep(const float* __restrict__ w, float* __restrict__ ww,
             int* __restrict__ counts, float* __restrict__ lossAcc,
             unsigned short* __restrict__ wfrag, int* __restrict__ donecnt)
{
    const int t = threadIdx.x;
    if (blockIdx.x < 32) {
        const int ct = blockIdx.x;
        if (t < 256) {
            const int part = t >> 7, q = (t >> 6) & 1, lf = t & 63;
            const int n = lf & 15, k = ct * 16 + n;
            const float* wk = w + (size_t)k * DIM;
            unsigned short v8[8];
            #pragma unroll
            for (int j8 = 0; j8 < 8; ++j8) {
                const int d = q * 32 + ((lf >> 4) << 3) + j8;
                float v = wk[d];
                unsigned int hb = __float_as_uint(v) & 0xFFFF0000u;
                if (part == 0) {
                    v8[j8] = (unsigned short)(hb >> 16);
                } else {
                    float rr = v - __uint_as_float(hb);    // exact residual
                    v8[j8] = (unsigned short)(__float_as_uint(rr) >> 16);
                }
            }
            bf16x8* dst = reinterpret_cast<bf16x8*>(wfrag);
            dst[((part * 32 + ct) * 2 + q) * 64 + lf] =
                *reinterpret_cast<const bf16x8*>(v8);
        }
    } else {
        // block 32: ww[k] in the exact numpy pairwise order + zero-init
        const int k = t;                       // 512 threads = codes
        const float* wk = w + (size_t)k * DIM;
        float r[8];
        #pragma unroll
        for (int i = 0; i < 8; ++i) {
            #pragma unroll
            for (int j = 0; j < 8; ++j) {
                float v = wk[i * 8 + j];
                float pp = __fmul_rn(v, v);
                r[j] = (i == 0) ? pp : __fadd_rn(r[j], pp);
            }
        }
        ww[k] = tree8(r[0], r[1], r[2], r[3], r[4], r[5], r[6], r[7]);
        counts[k] = 0;
        if (k == 0) { *lossAcc = 0.0f; *donecnt = 0; }
    }
}

// R17 = R16 with the NT-store type fixed (ext_vector f32x4, not HIP float4).
// Theory under test (R16): vmcnt retires IN ISSUE ORDER, so each iteration's
// wait for the next FRAG loads also forces the previous iteration's zero-fill
// stores to retire (~600-1000cy ack under write pressure) -> loop throttles at
// store-ack latency. Depth-2 FRAG prefetch gives the wait two iterations of
// slack; NT stores skip L2 allocation (less wfrag/x eviction between sweeps).
// Finalize fused via donecnt last-block protocol (threadfence + atomic reads
// for cross-XCD coherence; identical double-prec reduction order).
// Screen/rescue math token-identical to R12-R15 (passing at 7.6e-6).
#define FRAG(PART, CT, Q) wf[((((PART) * 32 + (CT)) * 2 + (Q)) * 64) + l]

// 6 MFMAs of the hi/lo split screen for pos-tile PT against B-frags B0..B3
#define TILE6(PT, B0, B1, B2, B3, WWK)                                        \
    acc = (f32x4){(WWK), (WWK), (WWK), (WWK)};                                \
    acc = __builtin_amdgcn_mfma_f32_16x16x32_bf16(aL0[PT], B0, acc, 0, 0, 0); \
    acc = __builtin_amdgcn_mfma_f32_16x16x32_bf16(aH0[PT], B2, acc, 0, 0, 0); \
    acc = __builtin_amdgcn_mfma_f32_16x16x32_bf16(aH0[PT], B0, acc, 0, 0, 0); \
    acc = __builtin_amdgcn_mfma_f32_16x16x32_bf16(aL1[PT], B1, acc, 0, 0, 0); \
    acc = __builtin_amdgcn_mfma_f32_16x16x32_bf16(aH1[PT], B3, acc, 0, 0, 0); \
    acc = __builtin_amdgcn_mfma_f32_16x16x32_bf16(aH1[PT], B1, acc, 0, 0, 0);

extern "C" __global__ __launch_bounds__(TB)
__attribute__((amdgpu_waves_per_eu(2, 8)))
void vq_main(const float* __restrict__ x, const float* __restrict__ w,
             const float* __restrict__ ww, float* __restrict__ out,
             int* __restrict__ counts, float* __restrict__ lossAcc,
             const unsigned short* __restrict__ wfrag, int* __restrict__ donecnt)
{
    __shared__ __align__(16) float xtile[DIM][POSB + 1];  // 65792 B, <=2-way
    __shared__ float wwlds[KCODES];                       //  2048 B
    __shared__ int   hcount[KCODES];                      //  2048 B
    __shared__ int   ccount[POSB];                        //  1024 B
    __shared__ int   clist[POSB * 4];                     //  4096 B
    __shared__ int   bestkL[POSB];                        //  1024 B
    __shared__ int   lastFlag;

    const int tid = threadIdx.x;
    const int l   = tid & 63;                  // lane
    const int wv  = tid >> 6;                  // wave id
    const int n0  = blockIdx.x * POSB;         // 256 | 4096: one b per block
    const int b   = n0 >> 12;
    const int hw0 = n0 & 4095;

    hcount[tid]      = 0;
    hcount[tid + TB] = 0;
    ccount[tid]      = 0;
    wwlds[tid]       = ww[tid];                // staged once, coalesced
    wwlds[tid + TB]  = ww[tid + TB];

    // ---- A: cooperative x-tile load (fully coalesced: 256B/wave-instr)
    const float* xb = x + ((size_t)b * DIM) * HW + hw0;
    #pragma unroll
    for (int it = 0; it < 64; ++it) {
        const int idx = it * TB + tid;
        const int d = idx >> 8, ps = idx & 255;
        xtile[d][ps] = xb[(size_t)d * HW + ps];
    }
    __syncthreads();   // xtile + wwlds + ccount ready

    // ---- B: A-fragments of -2x for this wave's FOUR pos-tiles
    bf16x8 aH0[4], aH1[4], aL0[4], aL1[4];
    #pragma unroll
    for (int pt = 0; pt < 4; ++pt) {
        const int arow = (wv * 4 + pt) * 16 + (l & 15);
        #pragma unroll
        for (int q = 0; q < 2; ++q) {
            #pragma unroll
            for (int j8 = 0; j8 < 8; ++j8) {
                const int d = q * 32 + ((l >> 4) << 3) + j8;
                float v = xtile[d][arow];
                float m2 = -(v + v);                 // exact
                unsigned int hb = __float_as_uint(m2) & 0xFFFF0000u;
                float rr = m2 - __uint_as_float(hb);
                short hs = (short)(hb >> 16);
                short ls = (short)(__float_as_uint(rr) >> 16);
                if (q == 0) { aH0[pt][j8] = hs; aL0[pt][j8] = ls; }
                else        { aH1[pt][j8] = hs; aL1[pt][j8] = ls; }
            }
        }
    }

    const bf16x8* wf = reinterpret_cast<const bf16x8*>(wfrag);
    const int rloc = (l >> 4) << 2;            // acc[i] -> tile-local row rloc+i

    // encodings tile zero-fill setup (T0%4==1 -> +3 shift is 16B-aligned)
    const size_t T0 = ENC_OFF + (size_t)blockIdx.x * TILE_DW;
    f32x4* zs4 = reinterpret_cast<f32x4*>(out + T0 + 3);
    const f32x4 zero4 = (f32x4){0.0f, 0.0f, 0.0f, 0.0f};
    if (tid < 3)  out[T0 + tid] = 0.0f;              // edge dwords 0,1,2
    if (tid == 3) out[T0 + (TILE_DW - 1)] = 0.0f;    // edge dword 131071

    // ---- C: sweep 1 — running per-row min; FRAG prefetch depth 2 so the
    // load-wait never forces <2-iteration-old stores to retire (vmcnt is
    // in-issue-order); zero-fill via nontemporal f32x4 stores.
    float rmin[4][4];
    #pragma unroll
    for (int pt = 0; pt < 4; ++pt)
        #pragma unroll
        for (int i = 0; i < 4; ++i) rmin[pt][i] = INFINITY;
    {
        bf16x8 c0 = FRAG(0, 0, 0), c1 = FRAG(0, 0, 1);
        bf16x8 c2 = FRAG(1, 0, 0), c3 = FRAG(1, 0, 1);
        bf16x8 d0 = FRAG(0, 1, 0), d1 = FRAG(0, 1, 1);
        bf16x8 d2 = FRAG(1, 1, 0), d3 = FRAG(1, 1, 1);
        float wa = wwlds[(l & 15)];
        float wbn = wwlds[16 + (l & 15)];
        f32x4 acc;
        #pragma unroll 1
        for (int ct = 0; ct < 32; ++ct) {
            const int ft = (ct + 2) & 31;                // tail wraps; harmless
            bf16x8 e0 = FRAG(0, ft, 0), e1 = FRAG(0, ft, 1);
            bf16x8 e2 = FRAG(1, ft, 0), e3 = FRAG(1, ft, 1);
            float wc = wwlds[ft * 16 + (l & 15)];
            #pragma unroll
            for (int pt = 0; pt < 4; ++pt) {
                TILE6(pt, c0, c1, c2, c3, wa)
                #pragma unroll
                for (int i = 0; i < 4; ++i)
                    rmin[pt][i] = fminf(rmin[pt][i], acc[i]);
            }
            {   // zero-fill interleave: 4 NT f32x4/thread/iter -> [0, 16384)
                const int mb = ct * (TB * 2) + tid;
                __builtin_nontemporal_store(zero4, &zs4[mb]);
                __builtin_nontemporal_store(zero4, &zs4[mb + TB]);
                const int mb2 = (TB * 64) + ct * (TB * 2) + tid;
                __builtin_nontemporal_store(zero4, &zs4[mb2]);
                __builtin_nontemporal_store(zero4, &zs4[mb2 + TB]);
            }
            c0 = d0; c1 = d1; c2 = d2; c3 = d3; wa = wbn;
            d0 = e0; d1 = e1; d2 = e2; d3 = e3; wbn = wc;
        }
    }
    // col-reduce: 16-lane butterfly (lanes sharing l>>4 hold cols 0..15)
    float thr[4][4];
    #pragma unroll
    for (int pt = 0; pt < 4; ++pt) {
        #pragma unroll
        for (int mm = 1; mm < 16; mm <<= 1)
            #pragma unroll
            for (int i = 0; i < 4; ++i)
                rmin[pt][i] = fminf(rmin[pt][i], __shfl_xor(rmin[pt][i], mm));
        #pragma unroll
        for (int i = 0; i < 4; ++i) thr[pt][i] = rmin[pt][i] + TAU;
    }

    // ---- D: sweep 2 — bit-identical recompute, candidate append vs thr
    {
        bf16x8 c0 = FRAG(0, 0, 0), c1 = FRAG(0, 0, 1);
        bf16x8 c2 = FRAG(1, 0, 0), c3 = FRAG(1, 0, 1);
        bf16x8 d0 = FRAG(0, 1, 0), d1 = FRAG(0, 1, 1);
        bf16x8 d2 = FRAG(1, 1, 0), d3 = FRAG(1, 1, 1);
        float wa = wwlds[(l & 15)];
        float wbn = wwlds[16 + (l & 15)];
        f32x4 acc;
        #pragma unroll 1
        for (int ct = 0; ct < 32; ++ct) {
            const int ft = (ct + 2) & 31;
            bf16x8 e0 = FRAG(0, ft, 0), e1 = FRAG(0, ft, 1);
            bf16x8 e2 = FRAG(1, ft, 0), e3 = FRAG(1, ft, 1);
            float wc = wwlds[ft * 16 + (l & 15)];
            #pragma unroll
            for (int pt = 0; pt < 4; ++pt) {
                TILE6(pt, c0, c1, c2, c3, wa)
                const int prow = (wv * 4 + pt) * 16 + rloc;
                #pragma unroll
                for (int i = 0; i < 4; ++i) {
                    if (acc[i] <= thr[pt][i]) {
                        int s = atomicAdd(&ccount[prow + i], 1);
                        if (s < 4) clist[(prow + i) * 4 + s] = ct * 16 + (l & 15);
                    }
                }
            }
            {   // zero-fill second half -> [16384, 32768), guard the edge
                const int mb = 16384 + ct * (TB * 2) + tid;
                __builtin_nontemporal_store(zero4, &zs4[mb]);
                if (mb + TB < NF4)
                    __builtin_nontemporal_store(zero4, &zs4[mb + TB]);
                const int mb2 = 16384 + (TB * 64) + ct * (TB * 2) + tid;
                if (mb2 < NF4)
                    __builtin_nontemporal_store(zero4, &zs4[mb2]);
                if (mb2 + TB < NF4)
                    __builtin_nontemporal_store(zero4, &zs4[mb2 + TB]);
            }
            c0 = d0; c1 = d1; c2 = d2; c3 = d3; wa = wbn;
            d0 = e0; d1 = e1; d2 = e2; d3 = e3; wbn = wc;
        }
    }

    __syncthreads();   // clists complete; zero-fill drained (vmcnt(0) at barrier)

    // ---- E: rescue — wave wv owns positions wv*64 .. wv*64+63 (lane = one)
    {
        const int p = wv * 64 + l;             // position within block
        const int cnt = ccount[p];
        int bk;
        if (cnt == 1) {
            bk = clist[p * 4 + 0];
        } else {
            float x2c[DIM];
            float r[8];
            #pragma unroll
            for (int d = 0; d < DIM; ++d) {
                float v = xtile[d][p];
                x2c[d] = v + v;                  // exact doubling
                float pp = __fmul_rn(v, v);
                r[d & 7] = (d < 8) ? pp : __fadd_rn(r[d & 7], pp);
            }
            const float A = tree8(r[0], r[1], r[2], r[3], r[4], r[5], r[6], r[7]);
            if (cnt <= 4) {
                float bd = INFINITY; int bk2 = KCODES;
                for (int c = 0; c < cnt; ++c) {
                    const int k = clist[p * 4 + c];
                    const float* wk = w + (size_t)k * DIM;
                    float s[8];
                    #pragma unroll
                    for (int i = 0; i < 8; ++i) {
                        #pragma unroll
                        for (int j = 0; j < 8; ++j) {
                            const int d = i * 8 + j;
                            float wvv = wk[d];
                            if (i == 0) s[j] = __fmul_rn(x2c[d], wvv);
                            else        s[j] = __fmaf_rn(x2c[d], wvv, s[j]);
                        }
                    }
                    float dot  = tree8(s[0], s[1], s[2], s[3], s[4], s[5], s[6], s[7]);
                    float dist = __fadd_rn(__fadd_rn(A, wwlds[k]), -dot);
                    if (dist < bd || (dist == bd && k < bk2)) { bd = dist; bk2 = k; }
                }
                bk = bk2;
            } else {                             // guaranteed path (≈never)
                float bd = INFINITY; int bk2 = 0;
                #pragma unroll 1
                for (int k = 0; k < KCODES; ++k) {
                    const float* wk = w + (size_t)k * DIM;
                    float s[8];
                    #pragma unroll
                    for (int i = 0; i < 8; ++i) {
                        #pragma unroll
                        for (int j = 0; j < 8; ++j) {
                            const int d = i * 8 + j;
                            float wvv = wk[d];
                            if (i == 0) s[j] = __fmul_rn(x2c[d], wvv);
                            else        s[j] = __fmaf_rn(x2c[d], wvv, s[j]);
                        }
                    }
                    float dot  = tree8(s[0], s[1], s[2], s[3], s[4], s[5], s[6], s[7]);
                    float dist = __fadd_rn(__fadd_rn(A, wwlds[k]), -dot);
                    if (dist < bd) { bd = dist; bk2 = k; }   // ascending strict <
                }
                bk = bk2;
            }
        }
        bestkL[p] = bk;
        out[ENC_OFF + (size_t)(n0 + p) * KCODES + bk] = 1.0f;   // one-hot
        atomicAdd(&hcount[bk], 1);
    }

    __syncthreads();   // bestkL visible; hcount atomics ordered before drain

    // ---- F: parallel epilogue — thread tid owns position tid (64 channels)
    {
        const int sp = tid;
        const int bk = bestkL[sp];
        const float4* wr = reinterpret_cast<const float4*>(w + (size_t)bk * DIM);
        float* qo = out + ((size_t)b * DIM) * HW + (hw0 + sp);
        float sse = 0.0f;
        #pragma unroll
        for (int c = 0; c < 16; ++c) {
            float4 qv = wr[c];
            const int ch = c * 4;
            qo[(size_t)(ch + 0) * HW] = qv.x;
            qo[(size_t)(ch + 1) * HW] = qv.y;
            qo[(size_t)(ch + 2) * HW] = qv.z;
            qo[(size_t)(ch + 3) * HW] = qv.w;
            float e0 = qv.x - xtile[ch + 0][sp]; sse = __fmaf_rn(e0, e0, sse);
            float e1 = qv.y - xtile[ch + 1][sp]; sse = __fmaf_rn(e1, e1, sse);
            float e2 = qv.z - xtile[ch + 2][sp]; sse = __fmaf_rn(e2, e2, sse);
            float e3 = qv.w - xtile[ch + 3][sp]; sse = __fmaf_rn(e3, e3, sse);
        }
        #pragma unroll
        for (int off = 32; off > 0; off >>= 1) sse += __shfl_down(sse, off);
        if (l == 0) atomicAdd(lossAcc, sse);
    }

    __syncthreads();   // all hcount traffic done

    // histogram drain
    {
        int c0 = hcount[tid];       if (c0) atomicAdd(&counts[tid], c0);
        int c1 = hcount[tid + TB];  if (c1) atomicAdd(&counts[tid + TB], c1);
    }
    __syncthreads();   // drain atomics issued by all threads

    // ---- G: fused finalize — last block computes loss + perplexity.
    __threadfence();   // counts/lossAcc atomics globally visible before signal
    if (tid == 0)
        lastFlag = (atomicAdd(donecnt, 1) == NBLK - 1) ? 1 : 0;
    __syncthreads();
    if (lastFlag) {
        __threadfence();                       // acquire side
        double* sred = reinterpret_cast<double*>(&xtile[0][0]);  // xtile dead
        #pragma unroll
        for (int u = 0; u < 2; ++u) {
            const int k = u * TB + tid;
            int cv = atomicAdd(&counts[k], 0); // coherent cross-XCD read
            double p = (double)cv * (1.0 / (double)NPOS);
            sred[k] = -p * log(p + 1e-10);
        }
        __syncthreads();
        for (int s = KCODES / 2; s > 0; s >>= 1) {
            if (tid < s) sred[tid] += sred[tid + s];
            __syncthreads();
        }
        if (tid == 0) {
            float lossv = atomicAdd(lossAcc, 0.0f);   // coherent read
            out[PERP_OFF] = (float)exp(sred[0]);
            out[LOSS_OFF] = 1.25f * (lossv / 8388608.0f);
        }
    }
}

extern "C" void kernel_launch(void* const* d_in, const int* in_sizes, int n_in,
                              void* d_out, int out_size, void* d_ws, size_t ws_size,
                              hipStream_t stream)
{
    const float* x = (const float*)d_in[0];    // [32,64,64,64] fp32
    const float* w = (const float*)d_in[1];    // [512,64] fp32
    float* out = (float*)d_out;

    float* ww              = (float*)d_ws;                       // 512 floats
    int*   counts          = (int*)((char*)d_ws + 2048);         // 512 ints
    float* lossAcc         = (float*)((char*)d_ws + 4096);       // 1 float
    int*   donecnt         = (int*)((char*)d_ws + 4104);         // 1 int
    unsigned short* wfrag  = (unsigned short*)((char*)d_ws + 8192);  // 128KB

    vq_prep<<<33, 512, 0, stream>>>(w, ww, counts, lossAcc, wfrag, donecnt);
    vq_main<<<NBLK, TB, 0, stream>>>(x, w, ww, out, counts,
                                     lossAcc, wfrag, donecnt);
}

// Round 12
// 389.901 us; speedup vs baseline: 1.2391x; 1.2391x over previous
//
#include <hip/hip_runtime.h>
#include <math.h>

// ---- problem constants ----
#define TB        256           // threads per block = 4 waves
#define POSB      256           // positions per block (4 waves x 4 pos-tiles x 16)
#define NPOS      131072        // B*H*W positions
#define KCODES    512
#define DIM       64
#define HW        4096          // H*W
#define LOSS_OFF  8388608ull
#define ENC_OFF   8388609ull
#define PERP_OFF  75497473ull
#define TILE_DW   (POSB * KCODES)       // 131072 dwords: block's encodings tile
#define NF4       ((TILE_DW - 4) / 4)   // 32767 float4 after the +3 align shift
#define TAU       2.0e-4f               // rigorous screen slack (R12 notes)
#define NBLK      (NPOS / POSB)         // 512 main blocks

typedef __attribute__((ext_vector_type(8))) short bf16x8;   // 8 bf16 = 4 VGPR
typedef __attribute__((ext_vector_type(4))) float f32x4;

__device__ __forceinline__ float tree8(float r0, float r1, float r2, float r3,
                                       float r4, float r5, float r6, float r7) {
    // numpy pairwise combine: ((r0+r1)+(r2+r3)) + ((r4+r5)+(r6+r7))
    return __fadd_rn(__fadd_rn(__fadd_rn(r0, r1), __fadd_rn(r2, r3)),
                     __fadd_rn(__fadd_rn(r4, r5), __fadd_rn(r6, r7)));
}

// Prep (R15-parallel, proven): blocks 0..31 pack code-tile ct's B-fragments
// with coalesced 16B stores; block 32 does exact pairwise ww + zero-init.
// Fragment convention identical to R12-R15: lane lf holds col n=lf&15,
// kslot=(lf>>4)*8+j8, channel d=q*32+kslot; hi=top-16-bits, lo=trunc(v-hi).
extern "C" __global__ __launch_bounds__(512)
void vq_prep(const float* __restrict__ w, float* __restrict__ ww,
             int* __restrict__ counts, float* __restrict__ lossAcc,
             unsigned short* __restrict__ wfrag)
{
    const int t = threadIdx.x;
    if (blockIdx.x < 32) {
        const int ct = blockIdx.x;
        if (t < 256) {
            const int part = t >> 7, q = (t >> 6) & 1, lf = t & 63;
            const int n = lf & 15, k = ct * 16 + n;
            const float* wk = w + (size_t)k * DIM;
            unsigned short v8[8];
            #pragma unroll
            for (int j8 = 0; j8 < 8; ++j8) {
                const int d = q * 32 + ((lf >> 4) << 3) + j8;
                float v = wk[d];
                unsigned int hb = __float_as_uint(v) & 0xFFFF0000u;
                if (part == 0) {
                    v8[j8] = (unsigned short)(hb >> 16);
                } else {
                    float rr = v - __uint_as_float(hb);    // exact residual
                    v8[j8] = (unsigned short)(__float_as_uint(rr) >> 16);
                }
            }
            bf16x8* dst = reinterpret_cast<bf16x8*>(wfrag);
            dst[((part * 32 + ct) * 2 + q) * 64 + lf] =
                *reinterpret_cast<const bf16x8*>(v8);
        }
    } else {
        // block 32: ww[k] in the exact numpy pairwise order + zero-init
        const int k = t;                       // 512 threads = codes
        const float* wk = w + (size_t)k * DIM;
        float r[8];
        #pragma unroll
        for (int i = 0; i < 8; ++i) {
            #pragma unroll
            for (int j = 0; j < 8; ++j) {
                float v = wk[i * 8 + j];
                float pp = __fmul_rn(v, v);
                r[j] = (i == 0) ? pp : __fadd_rn(r[j], pp);
            }
        }
        ww[k] = tree8(r[0], r[1], r[2], r[3], r[4], r[5], r[6], r[7]);
        counts[k] = 0;
        if (k == 0) *lossAcc = 0.0f;
    }
}

// R18: phase-separated encodings stream, NT stores REVERTED.
// R17 post-mortem: NT stores bypass L2 while the one-hot scatter takes the
// coherent path -> undefined merge order, absmax 1.0 (+150MB write amp).
// First direct counters: Mfma 9% / VALU 11% / HBM 2.2TB/s -> pure stall.
// Fix: after rescue, bestkL for all 256 positions is in LDS, so the block
// writes its ENTIRE 512KB enc tile in one store-only streaming phase with
// the 1.0 inserted in-register (R14's vq_enc logic, proven at 7.6e-6) —
// no scattered RMW one-hots, sweeps become pure load+MFMA (clean counted
// vmcnt, depth-2 prefetch kept), stores run at fill-rate shape and overlap
// other blocks' compute. Finalize back to the separate proven kernel.
// Screen/rescue math token-identical to R12-R15.
#define FRAG(PART, CT, Q) wf[((((PART) * 32 + (CT)) * 2 + (Q)) * 64) + l]

// 6 MFMAs of the hi/lo split screen for pos-tile PT against B-frags B0..B3
#define TILE6(PT, B0, B1, B2, B3, WWK)                                        \
    acc = (f32x4){(WWK), (WWK), (WWK), (WWK)};                                \
    acc = __builtin_amdgcn_mfma_f32_16x16x32_bf16(aL0[PT], B0, acc, 0, 0, 0); \
    acc = __builtin_amdgcn_mfma_f32_16x16x32_bf16(aH0[PT], B2, acc, 0, 0, 0); \
    acc = __builtin_amdgcn_mfma_f32_16x16x32_bf16(aH0[PT], B0, acc, 0, 0, 0); \
    acc = __builtin_amdgcn_mfma_f32_16x16x32_bf16(aL1[PT], B1, acc, 0, 0, 0); \
    acc = __builtin_amdgcn_mfma_f32_16x16x32_bf16(aH1[PT], B3, acc, 0, 0, 0); \
    acc = __builtin_amdgcn_mfma_f32_16x16x32_bf16(aH1[PT], B1, acc, 0, 0, 0);

extern "C" __global__ __launch_bounds__(TB)
__attribute__((amdgpu_waves_per_eu(2, 8)))
void vq_main(const float* __restrict__ x, const float* __restrict__ w,
             const float* __restrict__ ww, float* __restrict__ out,
             int* __restrict__ counts, float* __restrict__ lossAcc,
             const unsigned short* __restrict__ wfrag)
{
    __shared__ __align__(16) float xtile[DIM][POSB + 1];  // 65792 B, <=2-way
    __shared__ float wwlds[KCODES];                       //  2048 B
    __shared__ int   hcount[KCODES];                      //  2048 B
    __shared__ int   ccount[POSB];                        //  1024 B
    __shared__ int   clist[POSB * 4];                     //  4096 B
    __shared__ int   bestkL[POSB];                        //  1024 B

    const int tid = threadIdx.x;
    const int l   = tid & 63;                  // lane
    const int wv  = tid >> 6;                  // wave id
    const int n0  = blockIdx.x * POSB;         // 256 | 4096: one b per block
    const int b   = n0 >> 12;
    const int hw0 = n0 & 4095;

    hcount[tid]      = 0;
    hcount[tid + TB] = 0;
    ccount[tid]      = 0;
    wwlds[tid]       = ww[tid];                // staged once, coalesced
    wwlds[tid + TB]  = ww[tid + TB];

    // ---- A: cooperative x-tile load (fully coalesced: 256B/wave-instr)
    const float* xb = x + ((size_t)b * DIM) * HW + hw0;
    #pragma unroll
    for (int it = 0; it < 64; ++it) {
        const int idx = it * TB + tid;
        const int d = idx >> 8, ps = idx & 255;
        xtile[d][ps] = xb[(size_t)d * HW + ps];
    }
    __syncthreads();   // xtile + wwlds + ccount ready

    // ---- B: A-fragments of -2x for this wave's FOUR pos-tiles
    bf16x8 aH0[4], aH1[4], aL0[4], aL1[4];
    #pragma unroll
    for (int pt = 0; pt < 4; ++pt) {
        const int arow = (wv * 4 + pt) * 16 + (l & 15);
        #pragma unroll
        for (int q = 0; q < 2; ++q) {
            #pragma unroll
            for (int j8 = 0; j8 < 8; ++j8) {
                const int d = q * 32 + ((l >> 4) << 3) + j8;
                float v = xtile[d][arow];
                float m2 = -(v + v);                 // exact
                unsigned int hb = __float_as_uint(m2) & 0xFFFF0000u;
                float rr = m2 - __uint_as_float(hb);
                short hs = (short)(hb >> 16);
                short ls = (short)(__float_as_uint(rr) >> 16);
                if (q == 0) { aH0[pt][j8] = hs; aL0[pt][j8] = ls; }
                else        { aH1[pt][j8] = hs; aL1[pt][j8] = ls; }
            }
        }
    }

    const bf16x8* wf = reinterpret_cast<const bf16x8*>(wfrag);
    const int rloc = (l >> 4) << 2;            // acc[i] -> tile-local row rloc+i

    // ---- C: sweep 1 — running per-row min; PURE load+MFMA loop (no stores),
    // FRAG prefetch depth 2.
    float rmin[4][4];
    #pragma unroll
    for (int pt = 0; pt < 4; ++pt)
        #pragma unroll
        for (int i = 0; i < 4; ++i) rmin[pt][i] = INFINITY;
    {
        bf16x8 c0 = FRAG(0, 0, 0), c1 = FRAG(0, 0, 1);
        bf16x8 c2 = FRAG(1, 0, 0), c3 = FRAG(1, 0, 1);
        bf16x8 d0 = FRAG(0, 1, 0), d1 = FRAG(0, 1, 1);
        bf16x8 d2 = FRAG(1, 1, 0), d3 = FRAG(1, 1, 1);
        float wa = wwlds[(l & 15)];
        float wbn = wwlds[16 + (l & 15)];
        f32x4 acc;
        #pragma unroll 1
        for (int ct = 0; ct < 32; ++ct) {
            const int ft = (ct + 2) & 31;                // tail wraps; harmless
            bf16x8 e0 = FRAG(0, ft, 0), e1 = FRAG(0, ft, 1);
            bf16x8 e2 = FRAG(1, ft, 0), e3 = FRAG(1, ft, 1);
            float wc = wwlds[ft * 16 + (l & 15)];
            #pragma unroll
            for (int pt = 0; pt < 4; ++pt) {
                TILE6(pt, c0, c1, c2, c3, wa)
                #pragma unroll
                for (int i = 0; i < 4; ++i)
                    rmin[pt][i] = fminf(rmin[pt][i], acc[i]);
            }
            c0 = d0; c1 = d1; c2 = d2; c3 = d3; wa = wbn;
            d0 = e0; d1 = e1; d2 = e2; d3 = e3; wbn = wc;
        }
    }
    // col-reduce: 16-lane butterfly (lanes sharing l>>4 hold cols 0..15)
    float thr[4][4];
    #pragma unroll
    for (int pt = 0; pt < 4; ++pt) {
        #pragma unroll
        for (int mm = 1; mm < 16; mm <<= 1)
            #pragma unroll
            for (int i = 0; i < 4; ++i)
                rmin[pt][i] = fminf(rmin[pt][i], __shfl_xor(rmin[pt][i], mm));
        #pragma unroll
        for (int i = 0; i < 4; ++i) thr[pt][i] = rmin[pt][i] + TAU;
    }

    // ---- D: sweep 2 — bit-identical recompute, candidate append vs thr
    {
        bf16x8 c0 = FRAG(0, 0, 0), c1 = FRAG(0, 0, 1);
        bf16x8 c2 = FRAG(1, 0, 0), c3 = FRAG(1, 0, 1);
        bf16x8 d0 = FRAG(0, 1, 0), d1 = FRAG(0, 1, 1);
        bf16x8 d2 = FRAG(1, 1, 0), d3 = FRAG(1, 1, 1);
        float wa = wwlds[(l & 15)];
        float wbn = wwlds[16 + (l & 15)];
        f32x4 acc;
        #pragma unroll 1
        for (int ct = 0; ct < 32; ++ct) {
            const int ft = (ct + 2) & 31;
            bf16x8 e0 = FRAG(0, ft, 0), e1 = FRAG(0, ft, 1);
            bf16x8 e2 = FRAG(1, ft, 0), e3 = FRAG(1, ft, 1);
            float wc = wwlds[ft * 16 + (l & 15)];
            #pragma unroll
            for (int pt = 0; pt < 4; ++pt) {
                TILE6(pt, c0, c1, c2, c3, wa)
                const int prow = (wv * 4 + pt) * 16 + rloc;
                #pragma unroll
                for (int i = 0; i < 4; ++i) {
                    if (acc[i] <= thr[pt][i]) {
                        int s = atomicAdd(&ccount[prow + i], 1);
                        if (s < 4) clist[(prow + i) * 4 + s] = ct * 16 + (l & 15);
                    }
                }
            }
            c0 = d0; c1 = d1; c2 = d2; c3 = d3; wa = wbn;
            d0 = e0; d1 = e1; d2 = e2; d3 = e3; wbn = wc;
        }
    }

    __syncthreads();   // clists complete

    // ---- E: rescue — wave wv owns positions wv*64 .. wv*64+63 (lane = one)
    {
        const int p = wv * 64 + l;             // position within block
        const int cnt = ccount[p];
        int bk;
        if (cnt == 1) {
            bk = clist[p * 4 + 0];
        } else {
            float x2c[DIM];
            float r[8];
            #pragma unroll
            for (int d = 0; d < DIM; ++d) {
                float v = xtile[d][p];
                x2c[d] = v + v;                  // exact doubling
                float pp = __fmul_rn(v, v);
                r[d & 7] = (d < 8) ? pp : __fadd_rn(r[d & 7], pp);
            }
            const float A = tree8(r[0], r[1], r[2], r[3], r[4], r[5], r[6], r[7]);
            if (cnt <= 4) {
                float bd = INFINITY; int bk2 = KCODES;
                for (int c = 0; c < cnt; ++c) {
                    const int k = clist[p * 4 + c];
                    const float* wk = w + (size_t)k * DIM;
                    float s[8];
                    #pragma unroll
                    for (int i = 0; i < 8; ++i) {
                        #pragma unroll
                        for (int j = 0; j < 8; ++j) {
                            const int d = i * 8 + j;
                            float wvv = wk[d];
                            if (i == 0) s[j] = __fmul_rn(x2c[d], wvv);
                            else        s[j] = __fmaf_rn(x2c[d], wvv, s[j]);
                        }
                    }
                    float dot  = tree8(s[0], s[1], s[2], s[3], s[4], s[5], s[6], s[7]);
                    float dist = __fadd_rn(__fadd_rn(A, wwlds[k]), -dot);
                    if (dist < bd || (dist == bd && k < bk2)) { bd = dist; bk2 = k; }
                }
                bk = bk2;
            } else {                             // guaranteed path (≈never)
                float bd = INFINITY; int bk2 = 0;
                #pragma unroll 1
                for (int k = 0; k < KCODES; ++k) {
                    const float* wk = w + (size_t)k * DIM;
                    float s[8];
                    #pragma unroll
                    for (int i = 0; i < 8; ++i) {
                        #pragma unroll
                        for (int j = 0; j < 8; ++j) {
                            const int d = i * 8 + j;
                            float wvv = wk[d];
                            if (i == 0) s[j] = __fmul_rn(x2c[d], wvv);
                            else        s[j] = __fmaf_rn(x2c[d], wvv, s[j]);
                        }
                    }
                    float dot  = tree8(s[0], s[1], s[2], s[3], s[4], s[5], s[6], s[7]);
                    float dist = __fadd_rn(__fadd_rn(A, wwlds[k]), -dot);
                    if (dist < bd) { bd = dist; bk2 = k; }   // ascending strict <
                }
                bk = bk2;
            }
        }
        bestkL[p] = bk;
        atomicAdd(&hcount[bk], 1);
    }

    __syncthreads();   // bestkL visible; hcount atomics done

    // ---- F: quantized epilogue — thread tid owns position tid (64 channels)
    {
        const int sp = tid;
        const int bk = bestkL[sp];
        const float4* wr = reinterpret_cast<const float4*>(w + (size_t)bk * DIM);
        float* qo = out + ((size_t)b * DIM) * HW + (hw0 + sp);
        float sse = 0.0f;
        #pragma unroll
        for (int c = 0; c < 16; ++c) {
            float4 qv = wr[c];
            const int ch = c * 4;
            qo[(size_t)(ch + 0) * HW] = qv.x;
            qo[(size_t)(ch + 1) * HW] = qv.y;
            qo[(size_t)(ch + 2) * HW] = qv.z;
            qo[(size_t)(ch + 3) * HW] = qv.w;
            float e0 = qv.x - xtile[ch + 0][sp]; sse = __fmaf_rn(e0, e0, sse);
            float e1 = qv.y - xtile[ch + 1][sp]; sse = __fmaf_rn(e1, e1, sse);
            float e2 = qv.z - xtile[ch + 2][sp]; sse = __fmaf_rn(e2, e2, sse);
            float e3 = qv.w - xtile[ch + 3][sp]; sse = __fmaf_rn(e3, e3, sse);
        }
        #pragma unroll
        for (int off = 32; off > 0; off >>= 1) sse += __shfl_down(sse, off);
        if (l == 0) atomicAdd(lossAcc, sse);
    }

    // ---- G: streaming encodings write — whole 512KB tile, one-hot folded
    // in-register (R14 vq_enc logic, proven): pure coalesced f32x4 stores.
    {
        const size_t T0 = ENC_OFF + (size_t)blockIdx.x * TILE_DW;
        if (tid < 3)  out[T0 + tid] = (bestkL[0] == tid) ? 1.0f : 0.0f;
        if (tid == 3) out[T0 + (TILE_DW - 1)] =
                          (bestkL[POSB - 1] == (KCODES - 1)) ? 1.0f : 0.0f;
        f32x4* zs4 = reinterpret_cast<f32x4*>(out + T0 + 3);
        #pragma unroll 4
        for (int it = 0; it < 128; ++it) {
            const int m = it * TB + tid;       // 32768 slots cover 32767
            if (m < NF4) {
                const int o0 = 3 + 4 * m;      // in-tile dword of component 0
                const int pa = o0 >> 9,       ca = o0 & 511;
                const int pb = (o0 + 1) >> 9, cb = (o0 + 1) & 511;
                const int pc = (o0 + 2) >> 9, cc = (o0 + 2) & 511;
                const int pd = (o0 + 3) >> 9, cd = (o0 + 3) & 511;
                f32x4 v;
                v.x = (bestkL[pa] == ca) ? 1.0f : 0.0f;
                v.y = (bestkL[pb] == cb) ? 1.0f : 0.0f;
                v.z = (bestkL[pc] == cc) ? 1.0f : 0.0f;
                v.w = (bestkL[pd] == cd) ? 1.0f : 0.0f;
                zs4[m] = v;
            }
        }
    }

    // histogram drain (hcount final since the barrier after E)
    {
        int c0 = hcount[tid];       if (c0) atomicAdd(&counts[tid], c0);
        int c1 = hcount[tid + TB];  if (c1) atomicAdd(&counts[tid + TB], c1);
    }
}

// Finalize: loss scalar + perplexity from histogram (separate, proven).
extern "C" __global__ __launch_bounds__(512)
void vq_finalize(const int* __restrict__ counts, const float* __restrict__ lossAcc,
                 float* __restrict__ out)
{
    __shared__ double sred[KCODES];
    const int t = threadIdx.x;                 // 512 threads
    double p = (double)counts[t] * (1.0 / (double)NPOS);
    sred[t] = -p * log(p + 1e-10);
    __syncthreads();
    for (int s = KCODES / 2; s > 0; s >>= 1) {
        if (t < s) sred[t] += sred[t + s];
        __syncthreads();
    }
    if (t == 0) {
        out[PERP_OFF] = (float)exp(sred[0]);
        out[LOSS_OFF] = 1.25f * (lossAcc[0] / 8388608.0f);
    }
}

extern "C" void kernel_launch(void* const* d_in, const int* in_sizes, int n_in,
                              void* d_out, int out_size, void* d_ws, size_t ws_size,
                              hipStream_t stream)
{
    const float* x = (const float*)d_in[0];    // [32,64,64,64] fp32
    const float* w = (const float*)d_in[1];    // [512,64] fp32
    float* out = (float*)d_out;

    float* ww              = (float*)d_ws;                       // 512 floats
    int*   counts          = (int*)((char*)d_ws + 2048);         // 512 ints
    float* lossAcc         = (float*)((char*)d_ws + 4096);       // 1 float
    unsigned short* wfrag  = (unsigned short*)((char*)d_ws + 8192);  // 128KB

    vq_prep<<<33, 512, 0, stream>>>(w, ww, counts, lossAcc, wfrag);
    vq_main<<<NBLK, TB, 0, stream>>>(x, w, ww, out, counts, lossAcc, wfrag);
    vq_finalize<<<1, 512, 0, stream>>>(counts, lossAcc, out);
}